// Round 1
// baseline (1988.365 us; speedup 1.0000x reference)
//
#include <hip/hip_runtime.h>
#include <cmath>

#define S_TOTAL 32768   // BATCH*SEQ
#define LSEQ    2048
#define NBATCH  16
#define DM      256
#define DI      512
#define DSTATE  16
#define DTRANK  16
#define DXDBL   48      // DT_RANK + 2*D_STATE

// ---------------------------------------------------------------------------
// Generic tiled f32 GEMM: C[M,N] = epi(A[M,K] @ W[N,K]^T)
// BM=BN=64, BK=16, 256 threads, 4x4 micro-tile per thread.
// LDS stored k-major ([BK][BM]) so inner reads are float4 ds_read_b128.
// ---------------------------------------------------------------------------
enum { EPI_NONE = 0, EPI_SOFTPLUS_BIAS = 1, EPI_RESID = 2, EPI_GELU_BIAS = 3,
       EPI_BIAS_RESID = 4 };

__device__ __forceinline__ float gelu_exact(float x) {
    return 0.5f * x * (1.0f + erff(x * 0.70710678118654752440f));
}
__device__ __forceinline__ float softplus_f(float x) {
    return x > 20.0f ? x : log1pf(expf(x));
}

template <int EPI>
__global__ __launch_bounds__(256) void gemm_f32(
    const float* __restrict__ A, int lda,
    const float* __restrict__ W,           // [N,K] row-major
    const float* __restrict__ bias,        // [N] or null
    const float* __restrict__ resid, int ldr,
    float* __restrict__ C, int ldc,
    int M, int N, int K)
{
    __shared__ float As[16][64];
    __shared__ float Ws[16][64];

    const int tid  = threadIdx.x;
    const int brow = blockIdx.y * 64;
    const int bcol = blockIdx.x * 64;
    const int trow = (tid >> 4) << 2;      // 0..60
    const int tcol = (tid & 15) << 2;      // 0..60
    const int lr   = tid >> 2;             // 0..63 staging row
    const int lk   = (tid & 3) << 2;       // 0,4,8,12 staging k

    float acc[4][4] = {};

    for (int k0 = 0; k0 < K; k0 += 16) {
        // stage A tile (always in-bounds: M % 64 == 0, K % 16 == 0)
        {
            const float4 v = *(const float4*)(A + (size_t)(brow + lr) * lda + k0 + lk);
            As[lk + 0][lr] = v.x; As[lk + 1][lr] = v.y;
            As[lk + 2][lr] = v.z; As[lk + 3][lr] = v.w;
        }
        // stage W tile (guard rows >= N)
        {
            float4 v = make_float4(0.f, 0.f, 0.f, 0.f);
            if (bcol + lr < N)
                v = *(const float4*)(W + (size_t)(bcol + lr) * K + k0 + lk);
            Ws[lk + 0][lr] = v.x; Ws[lk + 1][lr] = v.y;
            Ws[lk + 2][lr] = v.z; Ws[lk + 3][lr] = v.w;
        }
        __syncthreads();

        #pragma unroll
        for (int kk = 0; kk < 16; ++kk) {
            const float4 av = *(const float4*)&As[kk][trow];
            const float4 wv = *(const float4*)&Ws[kk][tcol];
            acc[0][0] += av.x * wv.x; acc[0][1] += av.x * wv.y;
            acc[0][2] += av.x * wv.z; acc[0][3] += av.x * wv.w;
            acc[1][0] += av.y * wv.x; acc[1][1] += av.y * wv.y;
            acc[1][2] += av.y * wv.z; acc[1][3] += av.y * wv.w;
            acc[2][0] += av.z * wv.x; acc[2][1] += av.z * wv.y;
            acc[2][2] += av.z * wv.z; acc[2][3] += av.z * wv.w;
            acc[3][0] += av.w * wv.x; acc[3][1] += av.w * wv.y;
            acc[3][2] += av.w * wv.z; acc[3][3] += av.w * wv.w;
        }
        __syncthreads();
    }

    const int n0 = bcol + tcol;
    if (n0 >= N) return;                   // N % 4 == 0 so whole float4 valid
    #pragma unroll
    for (int i = 0; i < 4; ++i) {
        const int m = brow + trow + i;
        float vals[4];
        #pragma unroll
        for (int j = 0; j < 4; ++j) {
            float v = acc[i][j];
            if (EPI == EPI_SOFTPLUS_BIAS) {
                v = softplus_f(v + bias[n0 + j]);
            } else if (EPI == EPI_RESID) {
                v = v + resid[(size_t)m * ldr + n0 + j];
            } else if (EPI == EPI_GELU_BIAS) {
                v = gelu_exact(v + bias[n0 + j]);
            } else if (EPI == EPI_BIAS_RESID) {
                v = v + bias[n0 + j] + resid[(size_t)m * ldr + n0 + j];
            }
            vals[j] = v;
        }
        *(float4*)(C + (size_t)m * ldc + n0) =
            make_float4(vals[0], vals[1], vals[2], vals[3]);
    }
}

// ---------------------------------------------------------------------------
// Depthwise causal conv1d (width 4) + bias + SiLU.  One thread per (s, c).
// ---------------------------------------------------------------------------
__global__ __launch_bounds__(256) void conv_silu_kernel(
    const float* __restrict__ u, const float* __restrict__ cw,
    const float* __restrict__ cb, float* __restrict__ uc)
{
    const int idx = blockIdx.x * 256 + threadIdx.x;   // < S_TOTAL*DI
    const int c = idx & (DI - 1);
    const int s = idx >> 9;
    const int l = s & (LSEQ - 1);
    float acc = cb[c];
    #pragma unroll
    for (int t = 0; t < 4; ++t) {
        const int lt = l - 3 + t;
        if (lt >= 0)
            acc += u[(size_t)(s - 3 + t) * DI + c] * cw[c * 4 + t];
    }
    const float sig = 1.0f / (1.0f + __expf(-acc));
    uc[idx] = acc * sig;
}

// ---------------------------------------------------------------------------
// Selective scan.  Block = 256 threads = 4 waves; wave handles 4 channels
// (16 lanes per channel = one lane per state).  Sequential over L = 2048.
// Epilogue fused: y = (scan + uc*Dskip) * silu(z).  y aliases uc: every
// element is read by its lane group strictly before that group writes it.
// ---------------------------------------------------------------------------
__global__ __launch_bounds__(256) void scan_kernel(
    const float* delta, const float* uc, const float* xdbl, const float* z,
    const float* __restrict__ A_log, const float* __restrict__ Dskip,
    float* y)
{
    const int wave = threadIdx.x >> 6;
    const int lane = threadIdx.x & 63;
    const int b  = blockIdx.x >> 5;        // 16 batches
    const int cg = blockIdx.x & 31;        // 32 channel groups of 16
    const int c  = (cg << 4) + (wave << 2) + (lane >> 4);
    const int n  = lane & 15;

    const float a   = -__expf(A_log[c * DSTATE + n]);
    const float dsk = Dskip[c];
    float h = 0.0f;

    size_t off = (size_t)b * LSEQ * DI + c;
    size_t xo  = (size_t)b * LSEQ * DXDBL;

    float d  = delta[off];
    float u  = uc[off];
    float Bn = xdbl[xo + 16 + n];
    float Cn = xdbl[xo + 32 + n];
    float zz = z[off];

    for (int l = 0; l < LSEQ; ++l) {
        const size_t offN = off + DI;
        const size_t xoN  = xo + DXDBL;
        float dN = 0.f, uN = 0.f, BnN = 0.f, CnN = 0.f, zzN = 0.f;
        if (l < LSEQ - 1) {                // wave-uniform branch
            dN  = delta[offN];
            uN  = uc[offN];
            BnN = xdbl[xoN + 16 + n];
            CnN = xdbl[xoN + 32 + n];
            zzN = z[offN];
        }

        const float dA = __expf(d * a);
        h = h * dA + (d * u) * Bn;
        float yp = h * Cn;
        yp += __shfl_xor(yp, 1);
        yp += __shfl_xor(yp, 2);
        yp += __shfl_xor(yp, 4);
        yp += __shfl_xor(yp, 8);
        if (n == 0) {
            const float sig = 1.0f / (1.0f + __expf(-zz));
            y[off] = (yp + u * dsk) * (zz * sig);
        }

        d = dN; u = uN; Bn = BnN; Cn = CnN; zz = zzN;
        off = offN; xo = xoN;
    }
}

// ---------------------------------------------------------------------------
// LayerNorm over rows of 256.  One wave per row, 4 rows per block.
// ---------------------------------------------------------------------------
__global__ __launch_bounds__(256) void layernorm256_kernel(
    const float* __restrict__ in, const float* __restrict__ g,
    const float* __restrict__ b, float* __restrict__ out)
{
    const int wave = threadIdx.x >> 6;
    const int lane = threadIdx.x & 63;
    const int row  = blockIdx.x * 4 + wave;

    const float4 v = ((const float4*)(in + (size_t)row * DM))[lane];
    float s  = v.x + v.y + v.z + v.w;
    float sq = v.x * v.x + v.y * v.y + v.z * v.z + v.w * v.w;
    #pragma unroll
    for (int o = 1; o < 64; o <<= 1) {
        s  += __shfl_xor(s, o);
        sq += __shfl_xor(sq, o);
    }
    const float mu  = s * (1.0f / 256.0f);
    const float var = sq * (1.0f / 256.0f) - mu * mu;
    const float rs  = rsqrtf(var + 1e-12f);

    const float4 gg = ((const float4*)g)[lane];
    const float4 bb = ((const float4*)b)[lane];
    float4 o4;
    o4.x = (v.x - mu) * rs * gg.x + bb.x;
    o4.y = (v.y - mu) * rs * gg.y + bb.y;
    o4.z = (v.z - mu) * rs * gg.z + bb.z;
    o4.w = (v.w - mu) * rs * gg.w + bb.w;
    ((float4*)(out + (size_t)row * DM))[lane] = o4;
}

// ---------------------------------------------------------------------------
extern "C" void kernel_launch(void* const* d_in, const int* in_sizes, int n_in,
                              void* d_out, int out_size, void* d_ws, size_t ws_size,
                              hipStream_t stream)
{
    const float* x          = (const float*)d_in[0];
    const float* in_proj_w  = (const float*)d_in[1];
    const float* conv_w     = (const float*)d_in[2];
    const float* conv_b     = (const float*)d_in[3];
    const float* x_proj_w   = (const float*)d_in[4];
    const float* dt_proj_w  = (const float*)d_in[5];
    const float* dt_proj_b  = (const float*)d_in[6];
    const float* A_log      = (const float*)d_in[7];
    const float* Dskip      = (const float*)d_in[8];
    const float* out_proj_w = (const float*)d_in[9];
    const float* ln1_g      = (const float*)d_in[10];
    const float* ln1_b      = (const float*)d_in[11];
    const float* w1         = (const float*)d_in[12];
    const float* b1         = (const float*)d_in[13];
    const float* w2         = (const float*)d_in[14];
    const float* b2         = (const float*)d_in[15];
    const float* ln2_g      = (const float*)d_in[16];
    const float* ln2_b      = (const float*)d_in[17];
    float* out = (float*)d_out;
    float* ws  = (float*)d_ws;

    const size_t S = S_TOTAL;
    // Workspace layout (f32 elements), total = S*1584 floats ~= 198 MB.
    float* bufU  = ws;                    // [S,512] u -> delta -> (preLN1 | h1)
    float* bufZ  = ws + S * 512;          // [S,512] z -> (ff lower half)
    float* bufUC = ws + S * 1024;         // [S,512] uc -> y(in-place) -> ff upper
    float* bufXD = ws + S * 1536;         // [S,48]  x_dbl
    float* bufDelta = bufU;
    float* bufM  = bufU;                  // [S,256] mamba_out + x (pre-LN1)
    float* bufH1 = bufU + S * 256;        // [S,256] h1
    float* bufFF = bufZ;                  // [S,1024] gelu MLP hidden
    float* bufF2 = bufU;                  // [S,256] ff2 + b2 + h1 (pre-LN2)

    const dim3 blk(256);
    const int MB = S_TOTAL / 64;          // 512 row-tiles

    // 1) in_proj -> u, z   (two N=512 halves of the 1024-row weight)
    gemm_f32<EPI_NONE><<<dim3(8, MB), blk, 0, stream>>>(
        x, DM, in_proj_w, nullptr, nullptr, 0, bufU, DI, S_TOTAL, DI, DM);
    gemm_f32<EPI_NONE><<<dim3(8, MB), blk, 0, stream>>>(
        x, DM, in_proj_w + (size_t)DI * DM, nullptr, nullptr, 0, bufZ, DI, S_TOTAL, DI, DM);

    // 2) depthwise causal conv + SiLU
    conv_silu_kernel<<<dim3(S_TOTAL * DI / 256), blk, 0, stream>>>(
        bufU, conv_w, conv_b, bufUC);

    // 3) x_proj: uc @ x_proj_w^T -> [S,48]
    gemm_f32<EPI_NONE><<<dim3(1, MB), blk, 0, stream>>>(
        bufUC, DI, x_proj_w, nullptr, nullptr, 0, bufXD, DXDBL, S_TOTAL, DXDBL, DI);

    // 4) dt_proj + softplus -> delta  (K=16, A = x_dbl cols 0..15)
    gemm_f32<EPI_SOFTPLUS_BIAS><<<dim3(8, MB), blk, 0, stream>>>(
        bufXD, DXDBL, dt_proj_w, dt_proj_b, nullptr, 0, bufDelta, DI, S_TOTAL, DI, DTRANK);

    // 5) selective scan (+ Dskip + silu(z) gate), y written in-place over uc
    scan_kernel<<<dim3(NBATCH * 32), blk, 0, stream>>>(
        bufDelta, bufUC, bufXD, bufZ, A_log, Dskip, bufUC);

    // 6) out_proj + residual x -> pre-LN1
    gemm_f32<EPI_RESID><<<dim3(4, MB), blk, 0, stream>>>(
        bufUC, DI, out_proj_w, nullptr, x, DM, bufM, DM, S_TOTAL, DM, DI);

    // 7) LN1 -> h1
    layernorm256_kernel<<<dim3(S_TOTAL / 4), blk, 0, stream>>>(
        bufM, ln1_g, ln1_b, bufH1);

    // 8) ff1: gelu(h1 @ w1^T + b1) -> [S,1024]
    gemm_f32<EPI_GELU_BIAS><<<dim3(16, MB), blk, 0, stream>>>(
        bufH1, DM, w1, b1, nullptr, 0, bufFF, 1024, S_TOTAL, 1024, DM);

    // 9) ff2 + b2 + h1 -> pre-LN2
    gemm_f32<EPI_BIAS_RESID><<<dim3(4, MB), blk, 0, stream>>>(
        bufFF, 1024, w2, b2, bufH1, DM, bufF2, DM, S_TOTAL, DM, 1024);

    // 10) LN2 -> out
    layernorm256_kernel<<<dim3(S_TOTAL / 4), blk, 0, stream>>>(
        bufF2, ln2_g, ln2_b, out);
}

// Round 2
// 1395.044 us; speedup vs baseline: 1.4253x; 1.4253x over previous
//
#include <hip/hip_runtime.h>
#include <cmath>

#define S_TOTAL 32768   // BATCH*SEQ
#define LSEQ    2048
#define NBATCH  16
#define DM      256
#define DI      512
#define DSTATE  16
#define DTRANK  16
#define DXDBL   48      // DT_RANK + 2*D_STATE
#define NCHUNK  16
#define CHUNK   128     // LSEQ / NCHUNK

// ---------------------------------------------------------------------------
// Generic tiled f32 GEMM: C[M,N] = epi(A[M,K] @ W[N,K]^T)
// BM=BN=64, BK=16, 256 threads, 4x4 micro-tile per thread.
// ---------------------------------------------------------------------------
enum { EPI_NONE = 0, EPI_SOFTPLUS_BIAS = 1, EPI_RESID = 2, EPI_GELU_BIAS = 3,
       EPI_BIAS_RESID = 4 };

__device__ __forceinline__ float gelu_exact(float x) {
    return 0.5f * x * (1.0f + erff(x * 0.70710678118654752440f));
}
__device__ __forceinline__ float softplus_f(float x) {
    return x > 20.0f ? x : log1pf(expf(x));
}

template <int EPI>
__global__ __launch_bounds__(256) void gemm_f32(
    const float* __restrict__ A, int lda,
    const float* __restrict__ W,           // [N,K] row-major
    const float* __restrict__ bias,        // [N] or null
    const float* __restrict__ resid, int ldr,
    float* __restrict__ C, int ldc,
    int M, int N, int K)
{
    __shared__ float As[16][64];
    __shared__ float Ws[16][64];

    const int tid  = threadIdx.x;
    const int brow = blockIdx.y * 64;
    const int bcol = blockIdx.x * 64;
    const int trow = (tid >> 4) << 2;
    const int tcol = (tid & 15) << 2;
    const int lr   = tid >> 2;
    const int lk   = (tid & 3) << 2;

    float acc[4][4] = {};

    for (int k0 = 0; k0 < K; k0 += 16) {
        {
            const float4 v = *(const float4*)(A + (size_t)(brow + lr) * lda + k0 + lk);
            As[lk + 0][lr] = v.x; As[lk + 1][lr] = v.y;
            As[lk + 2][lr] = v.z; As[lk + 3][lr] = v.w;
        }
        {
            float4 v = make_float4(0.f, 0.f, 0.f, 0.f);
            if (bcol + lr < N)
                v = *(const float4*)(W + (size_t)(bcol + lr) * K + k0 + lk);
            Ws[lk + 0][lr] = v.x; Ws[lk + 1][lr] = v.y;
            Ws[lk + 2][lr] = v.z; Ws[lk + 3][lr] = v.w;
        }
        __syncthreads();

        #pragma unroll
        for (int kk = 0; kk < 16; ++kk) {
            const float4 av = *(const float4*)&As[kk][trow];
            const float4 wv = *(const float4*)&Ws[kk][tcol];
            acc[0][0] += av.x * wv.x; acc[0][1] += av.x * wv.y;
            acc[0][2] += av.x * wv.z; acc[0][3] += av.x * wv.w;
            acc[1][0] += av.y * wv.x; acc[1][1] += av.y * wv.y;
            acc[1][2] += av.y * wv.z; acc[1][3] += av.y * wv.w;
            acc[2][0] += av.z * wv.x; acc[2][1] += av.z * wv.y;
            acc[2][2] += av.z * wv.z; acc[2][3] += av.z * wv.w;
            acc[3][0] += av.w * wv.x; acc[3][1] += av.w * wv.y;
            acc[3][2] += av.w * wv.z; acc[3][3] += av.w * wv.w;
        }
        __syncthreads();
    }

    const int n0 = bcol + tcol;
    if (n0 >= N) return;
    #pragma unroll
    for (int i = 0; i < 4; ++i) {
        const int m = brow + trow + i;
        float vals[4];
        #pragma unroll
        for (int j = 0; j < 4; ++j) {
            float v = acc[i][j];
            if (EPI == EPI_SOFTPLUS_BIAS) {
                v = softplus_f(v + bias[n0 + j]);
            } else if (EPI == EPI_RESID) {
                v = v + resid[(size_t)m * ldr + n0 + j];
            } else if (EPI == EPI_GELU_BIAS) {
                v = gelu_exact(v + bias[n0 + j]);
            } else if (EPI == EPI_BIAS_RESID) {
                v = v + bias[n0 + j] + resid[(size_t)m * ldr + n0 + j];
            }
            vals[j] = v;
        }
        *(float4*)(C + (size_t)m * ldc + n0) =
            make_float4(vals[0], vals[1], vals[2], vals[3]);
    }
}

// ---------------------------------------------------------------------------
// Depthwise causal conv1d (width 4) + bias + SiLU.
// ---------------------------------------------------------------------------
__global__ __launch_bounds__(256) void conv_silu_kernel(
    const float* __restrict__ u, const float* __restrict__ cw,
    const float* __restrict__ cb, float* __restrict__ uc)
{
    const int idx = blockIdx.x * 256 + threadIdx.x;
    const int c = idx & (DI - 1);
    const int s = idx >> 9;
    const int l = s & (LSEQ - 1);
    float acc = cb[c];
    #pragma unroll
    for (int t = 0; t < 4; ++t) {
        const int lt = l - 3 + t;
        if (lt >= 0)
            acc += u[(size_t)(s - 3 + t) * DI + c] * cw[c * 4 + t];
    }
    const float sig = 1.0f / (1.0f + __expf(-acc));
    uc[idx] = acc * sig;
}

// ---------------------------------------------------------------------------
// Chunked selective scan (3 passes).  h' = h*dA + (d*u)*B is linear in h, so:
//   pass1: per chunk, P = prod(dA), Q = local final h (h0 = 0)
//   pass2: hs[k] = hs[k-1]*P[k-1] + Q[k-1]   (16-step sequential, tiny)
//   pass3: re-scan each chunk from hs[k], emit y (+Dskip, *silu(z) fused)
// Lane owns one channel x 4 states (float4): 4 independent exp/fma chains.
// Wave = 16 channels x 4 state-quads.  Block = 4 waves = 64 channels.
// Grid (p1/p3) = B * NCHUNK * (DI/64) = 2048 blocks -> 8 waves/SIMD.
// Unroll-by-2 with distance-2 prefetch hides load latency.
// ---------------------------------------------------------------------------
__global__ __launch_bounds__(256) void scan_p1(
    const float* __restrict__ delta, const float* __restrict__ uc,
    const float* __restrict__ xdbl, const float* __restrict__ A_log,
    float* __restrict__ P, float* __restrict__ Q)
{
    const int tid = threadIdx.x;
    const int cg = blockIdx.x & 7;
    const int k  = (blockIdx.x >> 3) & 15;
    const int b  = blockIdx.x >> 7;
    const int c  = (cg << 6) + (tid >> 2);
    const int nq = (tid & 3) << 2;

    const float4 al = *(const float4*)(A_log + c * DSTATE + nq);
    float4 a4;
    a4.x = -__expf(al.x); a4.y = -__expf(al.y);
    a4.z = -__expf(al.z); a4.w = -__expf(al.w);

    float4 h4 = {0, 0, 0, 0};
    float4 P4 = {1, 1, 1, 1};

    size_t off = ((size_t)(b * LSEQ + k * CHUNK)) * DI + c;
    size_t xo  = ((size_t)(b * LSEQ + k * CHUNK)) * DXDBL;

    float  dA_ = delta[off],      uA_ = uc[off];
    float4 BA_ = *(const float4*)(xdbl + xo + DTRANK + nq);
    float  dB_ = delta[off + DI], uB_ = uc[off + DI];
    float4 BB_ = *(const float4*)(xdbl + xo + DXDBL + DTRANK + nq);

    for (int l = 0; l < CHUNK; l += 2) {
        const size_t o2 = off + 2 * DI, x2 = xo + 2 * DXDBL;
        float  dC_ = 0.f, uC_ = 0.f, dD_ = 0.f, uD_ = 0.f;
        float4 BC_ = {0,0,0,0}, BD_ = {0,0,0,0};
        if (l + 2 < CHUNK) {
            dC_ = delta[o2];      uC_ = uc[o2];
            BC_ = *(const float4*)(xdbl + x2 + DTRANK + nq);
            dD_ = delta[o2 + DI]; uD_ = uc[o2 + DI];
            BD_ = *(const float4*)(xdbl + x2 + DXDBL + DTRANK + nq);
        }
        {   // step l
            float4 e;
            e.x = __expf(dA_ * a4.x); e.y = __expf(dA_ * a4.y);
            e.z = __expf(dA_ * a4.z); e.w = __expf(dA_ * a4.w);
            const float du = dA_ * uA_;
            h4.x = h4.x * e.x + du * BA_.x;
            h4.y = h4.y * e.y + du * BA_.y;
            h4.z = h4.z * e.z + du * BA_.z;
            h4.w = h4.w * e.w + du * BA_.w;
            P4.x *= e.x; P4.y *= e.y; P4.z *= e.z; P4.w *= e.w;
        }
        {   // step l+1
            float4 e;
            e.x = __expf(dB_ * a4.x); e.y = __expf(dB_ * a4.y);
            e.z = __expf(dB_ * a4.z); e.w = __expf(dB_ * a4.w);
            const float du = dB_ * uB_;
            h4.x = h4.x * e.x + du * BB_.x;
            h4.y = h4.y * e.y + du * BB_.y;
            h4.z = h4.z * e.z + du * BB_.z;
            h4.w = h4.w * e.w + du * BB_.w;
            P4.x *= e.x; P4.y *= e.y; P4.z *= e.z; P4.w *= e.w;
        }
        dA_ = dC_; uA_ = uC_; BA_ = BC_;
        dB_ = dD_; uB_ = uD_; BB_ = BD_;
        off = o2; xo = x2;
    }
    const size_t pi = (((size_t)(b * NCHUNK + k) * DI + c) << 4) + nq;
    *(float4*)(P + pi) = P4;
    *(float4*)(Q + pi) = h4;
}

__global__ __launch_bounds__(256) void scan_p2(
    const float* __restrict__ P, const float* __restrict__ Q,
    float* __restrict__ HS)
{
    const int t  = blockIdx.x * 256 + threadIdx.x;   // 32768
    const int nq = (t & 3) << 2;
    const int c  = (t >> 2) & (DI - 1);
    const int b  = t >> 11;
    float4 hs = {0, 0, 0, 0};
    for (int k = 0; k < NCHUNK; ++k) {
        const size_t idx = (((size_t)(b * NCHUNK + k) * DI + c) << 4) + nq;
        if (k > 0) {
            const size_t ip = idx - ((size_t)DI << 4);
            const float4 p4 = *(const float4*)(P + ip);
            const float4 q4 = *(const float4*)(Q + ip);
            hs.x = hs.x * p4.x + q4.x;
            hs.y = hs.y * p4.y + q4.y;
            hs.z = hs.z * p4.z + q4.z;
            hs.w = hs.w * p4.w + q4.w;
        }
        *(float4*)(HS + idx) = hs;
    }
}

__global__ __launch_bounds__(256) void scan_p3(
    const float* __restrict__ delta, const float* __restrict__ uc,
    const float* __restrict__ xdbl, const float* __restrict__ z,
    const float* __restrict__ A_log, const float* __restrict__ Dskip,
    const float* __restrict__ HS, float* __restrict__ y)
{
    const int tid = threadIdx.x;
    const int cg = blockIdx.x & 7;
    const int k  = (blockIdx.x >> 3) & 15;
    const int b  = blockIdx.x >> 7;
    const int c  = (cg << 6) + (tid >> 2);
    const int nq = (tid & 3) << 2;

    const float4 al = *(const float4*)(A_log + c * DSTATE + nq);
    float4 a4;
    a4.x = -__expf(al.x); a4.y = -__expf(al.y);
    a4.z = -__expf(al.z); a4.w = -__expf(al.w);
    const float dsk = Dskip[c];

    const size_t pi = (((size_t)(b * NCHUNK + k) * DI + c) << 4) + nq;
    float4 h4 = *(const float4*)(HS + pi);

    size_t off = ((size_t)(b * LSEQ + k * CHUNK)) * DI + c;
    size_t xo  = ((size_t)(b * LSEQ + k * CHUNK)) * DXDBL;

    float  dA_ = delta[off],      uA_ = uc[off],      zA_ = z[off];
    float4 BA_ = *(const float4*)(xdbl + xo + DTRANK + nq);
    float4 CA_ = *(const float4*)(xdbl + xo + DTRANK + DSTATE + nq);
    float  dB_ = delta[off + DI], uB_ = uc[off + DI], zB_ = z[off + DI];
    float4 BB_ = *(const float4*)(xdbl + xo + DXDBL + DTRANK + nq);
    float4 CB_ = *(const float4*)(xdbl + xo + DXDBL + DTRANK + DSTATE + nq);

    for (int l = 0; l < CHUNK; l += 2) {
        const size_t o2 = off + 2 * DI, x2 = xo + 2 * DXDBL;
        float  dC_ = 0.f, uC_ = 0.f, zC_ = 0.f, dD_ = 0.f, uD_ = 0.f, zD_ = 0.f;
        float4 BC_ = {0,0,0,0}, CC_ = {0,0,0,0}, BD_ = {0,0,0,0}, CD_ = {0,0,0,0};
        if (l + 2 < CHUNK) {
            dC_ = delta[o2];      uC_ = uc[o2];      zC_ = z[o2];
            BC_ = *(const float4*)(xdbl + x2 + DTRANK + nq);
            CC_ = *(const float4*)(xdbl + x2 + DTRANK + DSTATE + nq);
            dD_ = delta[o2 + DI]; uD_ = uc[o2 + DI]; zD_ = z[o2 + DI];
            BD_ = *(const float4*)(xdbl + x2 + DXDBL + DTRANK + nq);
            CD_ = *(const float4*)(xdbl + x2 + DXDBL + DTRANK + DSTATE + nq);
        }
        {   // step l
            float4 e;
            e.x = __expf(dA_ * a4.x); e.y = __expf(dA_ * a4.y);
            e.z = __expf(dA_ * a4.z); e.w = __expf(dA_ * a4.w);
            const float du = dA_ * uA_;
            h4.x = h4.x * e.x + du * BA_.x;
            h4.y = h4.y * e.y + du * BA_.y;
            h4.z = h4.z * e.z + du * BA_.z;
            h4.w = h4.w * e.w + du * BA_.w;
            float yp = h4.x * CA_.x + h4.y * CA_.y + h4.z * CA_.z + h4.w * CA_.w;
            yp += __shfl_xor(yp, 1);
            yp += __shfl_xor(yp, 2);
            if ((tid & 3) == 0) {
                const float sg = 1.0f / (1.0f + __expf(-zA_));
                y[off] = (yp + uA_ * dsk) * (zA_ * sg);
            }
        }
        {   // step l+1
            float4 e;
            e.x = __expf(dB_ * a4.x); e.y = __expf(dB_ * a4.y);
            e.z = __expf(dB_ * a4.z); e.w = __expf(dB_ * a4.w);
            const float du = dB_ * uB_;
            h4.x = h4.x * e.x + du * BB_.x;
            h4.y = h4.y * e.y + du * BB_.y;
            h4.z = h4.z * e.z + du * BB_.z;
            h4.w = h4.w * e.w + du * BB_.w;
            float yp = h4.x * CB_.x + h4.y * CB_.y + h4.z * CB_.z + h4.w * CB_.w;
            yp += __shfl_xor(yp, 1);
            yp += __shfl_xor(yp, 2);
            if ((tid & 3) == 0) {
                const float sg = 1.0f / (1.0f + __expf(-zB_));
                y[off + DI] = (yp + uB_ * dsk) * (zB_ * sg);
            }
        }
        dA_ = dC_; uA_ = uC_; zA_ = zC_; BA_ = BC_; CA_ = CC_;
        dB_ = dD_; uB_ = uD_; zB_ = zD_; BB_ = BD_; CB_ = CD_;
        off = o2; xo = x2;
    }
}

// ---------------------------------------------------------------------------
// LayerNorm over rows of 256.  One wave per row, 4 rows per block.
// ---------------------------------------------------------------------------
__global__ __launch_bounds__(256) void layernorm256_kernel(
    const float* __restrict__ in, const float* __restrict__ g,
    const float* __restrict__ b, float* __restrict__ out)
{
    const int wave = threadIdx.x >> 6;
    const int lane = threadIdx.x & 63;
    const int row  = blockIdx.x * 4 + wave;

    const float4 v = ((const float4*)(in + (size_t)row * DM))[lane];
    float s  = v.x + v.y + v.z + v.w;
    float sq = v.x * v.x + v.y * v.y + v.z * v.z + v.w * v.w;
    #pragma unroll
    for (int o = 1; o < 64; o <<= 1) {
        s  += __shfl_xor(s, o);
        sq += __shfl_xor(sq, o);
    }
    const float mu  = s * (1.0f / 256.0f);
    const float var = sq * (1.0f / 256.0f) - mu * mu;
    const float rs  = rsqrtf(var + 1e-12f);

    const float4 gg = ((const float4*)g)[lane];
    const float4 bb = ((const float4*)b)[lane];
    float4 o4;
    o4.x = (v.x - mu) * rs * gg.x + bb.x;
    o4.y = (v.y - mu) * rs * gg.y + bb.y;
    o4.z = (v.z - mu) * rs * gg.z + bb.z;
    o4.w = (v.w - mu) * rs * gg.w + bb.w;
    ((float4*)(out + (size_t)row * DM))[lane] = o4;
}

// ---------------------------------------------------------------------------
extern "C" void kernel_launch(void* const* d_in, const int* in_sizes, int n_in,
                              void* d_out, int out_size, void* d_ws, size_t ws_size,
                              hipStream_t stream)
{
    const float* x          = (const float*)d_in[0];
    const float* in_proj_w  = (const float*)d_in[1];
    const float* conv_w     = (const float*)d_in[2];
    const float* conv_b     = (const float*)d_in[3];
    const float* x_proj_w   = (const float*)d_in[4];
    const float* dt_proj_w  = (const float*)d_in[5];
    const float* dt_proj_b  = (const float*)d_in[6];
    const float* A_log      = (const float*)d_in[7];
    const float* Dskip      = (const float*)d_in[8];
    const float* out_proj_w = (const float*)d_in[9];
    const float* ln1_g      = (const float*)d_in[10];
    const float* ln1_b      = (const float*)d_in[11];
    const float* w1         = (const float*)d_in[12];
    const float* b1         = (const float*)d_in[13];
    const float* w2         = (const float*)d_in[14];
    const float* b2         = (const float*)d_in[15];
    const float* ln2_g      = (const float*)d_in[16];
    const float* ln2_b      = (const float*)d_in[17];
    float* out = (float*)d_out;
    float* ws  = (float*)d_ws;

    const size_t S = S_TOTAL;
    // Workspace layout (f32 elements), total = S*1584 floats ~= 207 MB.
    float* bufU  = ws;                    // [S,512] u -> delta -> (preLN1 | h1)
    float* bufZ  = ws + S * 512;          // [S,512] z -> (ff lower half)
    float* bufUC = ws + S * 1024;         // [S,512] uc -> y(in-place) -> ff upper
    float* bufXD = ws + S * 1536;         // [S,48]  x_dbl
    float* bufDelta = bufU;
    float* bufM  = bufU;                  // [S,256] mamba_out + x (pre-LN1)
    float* bufH1 = bufU + S * 256;        // [S,256] h1
    float* bufFF = bufZ;                  // [S,1024] gelu MLP hidden
    float* bufF2 = bufU;                  // [S,256] ff2 + b2 + h1 (pre-LN2)

    // Scan chunk buffers live in d_out (dead until final LN2 overwrites it):
    // 3 x [B][NCHUNK][DI][16] f32 = 25.2 MB < 33.5 MB out buffer.
    float* bufP  = out;
    float* bufQ  = out + (size_t)NBATCH * NCHUNK * DI * DSTATE;
    float* bufHS = out + (size_t)2 * NBATCH * NCHUNK * DI * DSTATE;

    const dim3 blk(256);
    const int MB = S_TOTAL / 64;          // 512 row-tiles

    // 1) in_proj -> u, z
    gemm_f32<EPI_NONE><<<dim3(8, MB), blk, 0, stream>>>(
        x, DM, in_proj_w, nullptr, nullptr, 0, bufU, DI, S_TOTAL, DI, DM);
    gemm_f32<EPI_NONE><<<dim3(8, MB), blk, 0, stream>>>(
        x, DM, in_proj_w + (size_t)DI * DM, nullptr, nullptr, 0, bufZ, DI, S_TOTAL, DI, DM);

    // 2) depthwise causal conv + SiLU
    conv_silu_kernel<<<dim3(S_TOTAL * DI / 256), blk, 0, stream>>>(
        bufU, conv_w, conv_b, bufUC);

    // 3) x_proj: uc @ x_proj_w^T -> [S,48]
    gemm_f32<EPI_NONE><<<dim3(1, MB), blk, 0, stream>>>(
        bufUC, DI, x_proj_w, nullptr, nullptr, 0, bufXD, DXDBL, S_TOTAL, DXDBL, DI);

    // 4) dt_proj + softplus -> delta
    gemm_f32<EPI_SOFTPLUS_BIAS><<<dim3(8, MB), blk, 0, stream>>>(
        bufXD, DXDBL, dt_proj_w, dt_proj_b, nullptr, 0, bufDelta, DI, S_TOTAL, DI, DTRANK);

    // 5) chunked selective scan; y written in-place over uc
    scan_p1<<<dim3(NBATCH * NCHUNK * (DI / 64)), blk, 0, stream>>>(
        bufDelta, bufUC, bufXD, A_log, bufP, bufQ);
    scan_p2<<<dim3(NBATCH * DI * 4 / 256), blk, 0, stream>>>(
        bufP, bufQ, bufHS);
    scan_p3<<<dim3(NBATCH * NCHUNK * (DI / 64)), blk, 0, stream>>>(
        bufDelta, bufUC, bufXD, bufZ, A_log, Dskip, bufHS, bufUC);

    // 6) out_proj + residual x -> pre-LN1
    gemm_f32<EPI_RESID><<<dim3(4, MB), blk, 0, stream>>>(
        bufUC, DI, out_proj_w, nullptr, x, DM, bufM, DM, S_TOTAL, DM, DI);

    // 7) LN1 -> h1
    layernorm256_kernel<<<dim3(S_TOTAL / 4), blk, 0, stream>>>(
        bufM, ln1_g, ln1_b, bufH1);

    // 8) ff1: gelu(h1 @ w1^T + b1) -> [S,1024]
    gemm_f32<EPI_GELU_BIAS><<<dim3(16, MB), blk, 0, stream>>>(
        bufH1, DM, w1, b1, nullptr, 0, bufFF, 1024, S_TOTAL, 1024, DM);

    // 9) ff2 + b2 + h1 -> pre-LN2
    gemm_f32<EPI_BIAS_RESID><<<dim3(4, MB), blk, 0, stream>>>(
        bufFF, 1024, w2, b2, bufH1, DM, bufF2, DM, S_TOTAL, DM, 1024);

    // 10) LN2 -> out
    layernorm256_kernel<<<dim3(S_TOTAL / 4), blk, 0, stream>>>(
        bufF2, ln2_g, ln2_b, out);
}

// Round 3
// 731.211 us; speedup vs baseline: 2.7193x; 1.9079x over previous
//
#include <hip/hip_runtime.h>
#include <cmath>

#define S_TOTAL 32768   // BATCH*SEQ
#define LSEQ    2048
#define NBATCH  16
#define DM      256
#define DI      512
#define DSTATE  16
#define DTRANK  16
#define XDLD    64      // padded row stride of x_dbl (48 valid cols)
#define NCHUNK  16
#define CHUNK   128     // LSEQ / NCHUNK

typedef __attribute__((ext_vector_type(8))) short short8;
typedef __attribute__((ext_vector_type(4))) float f32x4;

__device__ __forceinline__ unsigned short f2bf(float f) {
    union { float f; unsigned int u; } v; v.f = f;
    const unsigned int r = v.u + 0x7fffu + ((v.u >> 16) & 1u);
    return (unsigned short)(r >> 16);
}
__device__ __forceinline__ float bf2f(unsigned short h) {
    union { unsigned int u; float f; } v; v.u = ((unsigned int)h) << 16;
    return v.f;
}
__device__ __forceinline__ float gelu_exact(float x) {
    return 0.5f * x * (1.0f + erff(x * 0.70710678118654752440f));
}
__device__ __forceinline__ float softplus_f(float x) {
    return x > 20.0f ? x : log1pf(expf(x));
}

enum { EPI_NONE = 0, EPI_SOFTPLUS_BIAS = 1, EPI_RESID = 2, EPI_GELU_BIAS = 3,
       EPI_BIAS_RESID = 4 };

// ---------------------------------------------------------------------------
// bf16 MFMA GEMM: C[M,N] = epi(A[M,K](bf16) @ W[N,K](bf16)^T)
// 128x128 tile, BK=64, 4 waves (2x2), 16x16x32 MFMA, 4x4 frags/wave.
// global_load_lds(16B) staging, linear LDS dest, pre-swizzled global source
// (slot ^= row&7) + matching XOR on ds_read => 2-way banks (free).
// 2-phase pipeline: issue next-tile STAGE, compute current, 1 barrier/iter.
// M must be %128; N %128 (or guarded via nstore/nclampW for x_proj).
// ---------------------------------------------------------------------------
template <int EPI, bool OUTBF>
__global__ __launch_bounds__(256, 2) void gemm_bf16(
    const unsigned short* __restrict__ A, int lda,
    const unsigned short* __restrict__ W, int ldw,
    const float* __restrict__ bias,
    const float* __restrict__ resid, int ldr,
    void* __restrict__ Cout, int ldc, int nstore,
    int K, int nclampW)
{
    __shared__ unsigned short lds[2][2][8192];   // [buf][A/W][128*64] = 64 KB

    const int tid = threadIdx.x;
    const int w = tid >> 6, l = tid & 63;
    const int brow = blockIdx.y * 128, bcol = blockIdx.x * 128;
    const int wr = w >> 1, wc = w & 1;
    const int lr = l & 15, lh = l >> 4;

    f32x4 acc[4][4];
    #pragma unroll
    for (int m = 0; m < 4; ++m)
        #pragma unroll
        for (int n = 0; n < 4; ++n)
            acc[m][n] = f32x4{0.f, 0.f, 0.f, 0.f};

    auto stage = [&](int buf, int k0) {
        const int gslot = (l & 7) ^ (l >> 3);
        #pragma unroll
        for (int i = 0; i < 4; ++i) {
            const int row = i * 32 + w * 8 + (l >> 3);
            {   // A tile
                const unsigned short* g =
                    A + (size_t)(brow + row) * lda + k0 + gslot * 8;
                const unsigned short* lp = &lds[buf][0][i * 2048 + w * 512];
                __builtin_amdgcn_global_load_lds(
                    (const __attribute__((address_space(1))) void*)g,
                    (__attribute__((address_space(3))) void*)lp, 16, 0, 0);
            }
            {   // W tile (clamp rows beyond N)
                int grow = bcol + row; if (grow > nclampW) grow = nclampW;
                const unsigned short* g =
                    W + (size_t)grow * ldw + k0 + gslot * 8;
                const unsigned short* lp = &lds[buf][1][i * 2048 + w * 512];
                __builtin_amdgcn_global_load_lds(
                    (const __attribute__((address_space(1))) void*)g,
                    (__attribute__((address_space(3))) void*)lp, 16, 0, 0);
            }
        }
    };

    stage(0, 0);
    __syncthreads();

    const int nkt = K >> 6;
    for (int t = 0; t < nkt; ++t) {
        if (t + 1 < nkt) stage((t + 1) & 1, (t + 1) << 6);
        const unsigned short* la = &lds[t & 1][0][0];
        const unsigned short* lb = &lds[t & 1][1][0];
        #pragma unroll
        for (int kk = 0; kk < 2; ++kk) {
            short8 af[4], bw[4];
            #pragma unroll
            for (int m = 0; m < 4; ++m) {
                const int row = wr * 64 + m * 16 + lr;
                const int slot = (kk * 4 + lh) ^ (row & 7);
                af[m] = *(const short8*)(la + row * 64 + slot * 8);
            }
            #pragma unroll
            for (int n = 0; n < 4; ++n) {
                const int row = wc * 64 + n * 16 + lr;
                const int slot = (kk * 4 + lh) ^ (row & 7);
                bw[n] = *(const short8*)(lb + row * 64 + slot * 8);
            }
            #pragma unroll
            for (int m = 0; m < 4; ++m)
                #pragma unroll
                for (int n = 0; n < 4; ++n)
                    acc[m][n] = __builtin_amdgcn_mfma_f32_16x16x32_bf16(
                        af[m], bw[n], acc[m][n], 0, 0, 0);
        }
        __syncthreads();
    }

    // epilogue: D row = 4*lh + j, col = lr within each 16x16 fragment
    #pragma unroll
    for (int m = 0; m < 4; ++m) {
        #pragma unroll
        for (int j = 0; j < 4; ++j) {
            const int rg = brow + wr * 64 + m * 16 + lh * 4 + j;
            #pragma unroll
            for (int n = 0; n < 4; ++n) {
                const int cg = bcol + wc * 64 + n * 16 + lr;
                if (cg < nstore) {
                    float v = acc[m][n][j];
                    if (EPI == EPI_GELU_BIAS) {
                        v = gelu_exact(v + bias[cg]);
                    } else if (EPI == EPI_RESID) {
                        v += resid[(size_t)rg * ldr + cg];
                    } else if (EPI == EPI_BIAS_RESID) {
                        v += bias[cg] + resid[(size_t)rg * ldr + cg];
                    } else if (EPI == EPI_SOFTPLUS_BIAS) {
                        v = softplus_f(v + bias[cg]);
                    }
                    if (OUTBF)
                        ((unsigned short*)Cout)[(size_t)rg * ldc + cg] = f2bf(v);
                    else
                        ((float*)Cout)[(size_t)rg * ldc + cg] = v;
                }
            }
        }
    }
}

// ---------------------------------------------------------------------------
// f32 tiled GEMM (kept for dt_proj, K=16): C = softplus(A @ W^T + b)
// ---------------------------------------------------------------------------
template <int EPI>
__global__ __launch_bounds__(256) void gemm_f32(
    const float* __restrict__ A, int lda,
    const float* __restrict__ W,
    const float* __restrict__ bias,
    float* __restrict__ C, int ldc,
    int M, int N, int K)
{
    __shared__ float As[16][64];
    __shared__ float Ws[16][64];

    const int tid  = threadIdx.x;
    const int brow = blockIdx.y * 64;
    const int bcol = blockIdx.x * 64;
    const int trow = (tid >> 4) << 2;
    const int tcol = (tid & 15) << 2;
    const int lr   = tid >> 2;
    const int lk   = (tid & 3) << 2;

    float acc[4][4] = {};

    for (int k0 = 0; k0 < K; k0 += 16) {
        {
            const float4 v = *(const float4*)(A + (size_t)(brow + lr) * lda + k0 + lk);
            As[lk + 0][lr] = v.x; As[lk + 1][lr] = v.y;
            As[lk + 2][lr] = v.z; As[lk + 3][lr] = v.w;
        }
        {
            float4 v = make_float4(0.f, 0.f, 0.f, 0.f);
            if (bcol + lr < N)
                v = *(const float4*)(W + (size_t)(bcol + lr) * K + k0 + lk);
            Ws[lk + 0][lr] = v.x; Ws[lk + 1][lr] = v.y;
            Ws[lk + 2][lr] = v.z; Ws[lk + 3][lr] = v.w;
        }
        __syncthreads();
        #pragma unroll
        for (int kk = 0; kk < 16; ++kk) {
            const float4 av = *(const float4*)&As[kk][trow];
            const float4 wv = *(const float4*)&Ws[kk][tcol];
            acc[0][0] += av.x * wv.x; acc[0][1] += av.x * wv.y;
            acc[0][2] += av.x * wv.z; acc[0][3] += av.x * wv.w;
            acc[1][0] += av.y * wv.x; acc[1][1] += av.y * wv.y;
            acc[1][2] += av.y * wv.z; acc[1][3] += av.y * wv.w;
            acc[2][0] += av.z * wv.x; acc[2][1] += av.z * wv.y;
            acc[2][2] += av.z * wv.z; acc[2][3] += av.z * wv.w;
            acc[3][0] += av.w * wv.x; acc[3][1] += av.w * wv.y;
            acc[3][2] += av.w * wv.z; acc[3][3] += av.w * wv.w;
        }
        __syncthreads();
    }

    const int n0 = bcol + tcol;
    if (n0 >= N) return;
    #pragma unroll
    for (int i = 0; i < 4; ++i) {
        const int m = brow + trow + i;
        float vals[4];
        #pragma unroll
        for (int j = 0; j < 4; ++j) {
            float v = acc[i][j];
            if (EPI == EPI_SOFTPLUS_BIAS) v = softplus_f(v + bias[n0 + j]);
            vals[j] = v;
        }
        *(float4*)(C + (size_t)m * ldc + n0) =
            make_float4(vals[0], vals[1], vals[2], vals[3]);
    }
}

// ---------------------------------------------------------------------------
// Convert x (f32 -> bf16) and the 5 GEMM weight matrices.
// ---------------------------------------------------------------------------
__global__ __launch_bounds__(256) void convert_kernel(
    const float* __restrict__ x,   const float* __restrict__ win,
    const float* __restrict__ wxp, const float* __restrict__ wop,
    const float* __restrict__ w1,  const float* __restrict__ w2,
    unsigned short* __restrict__ x16, unsigned short* __restrict__ wb)
{
    int idx = blockIdx.x * 256 + threadIdx.x;
    const int NX = S_TOTAL * DM;                         // 8388608
    if (idx < NX) { x16[idx] = f2bf(x[idx]); return; }
    idx -= NX;
    if (idx < 262144) { wb[idx] = f2bf(win[idx]); return; }
    idx -= 262144;
    if (idx < 24576)  { wb[262144 + idx] = f2bf(wxp[idx]); return; }
    idx -= 24576;
    if (idx < 131072) { wb[286720 + idx] = f2bf(wop[idx]); return; }
    idx -= 131072;
    if (idx < 262144) { wb[417792 + idx] = f2bf(w1[idx]); return; }
    idx -= 262144;
    if (idx < 262144) { wb[679936 + idx] = f2bf(w2[idx]); return; }
}

// ---------------------------------------------------------------------------
// Depthwise causal conv1d (width 4, bf16 in) + bias + SiLU.
// Thread = 8 channels x 1 position. Writes f32 (scan) and bf16 (x_proj).
// ---------------------------------------------------------------------------
__global__ __launch_bounds__(256) void conv_silu_kernel(
    const unsigned short* __restrict__ u, const float* __restrict__ cw,
    const float* __restrict__ cb, float* __restrict__ uc32,
    unsigned short* __restrict__ uch)
{
    const int idx = blockIdx.x * 256 + threadIdx.x;   // < S_TOTAL*64
    const int g = idx & 63;
    const int s = idx >> 6;
    const int l = s & (LSEQ - 1);
    const int c0 = g * 8;

    float acc[8];
    float4 cwv[8];
    #pragma unroll
    for (int j = 0; j < 8; ++j) {
        acc[j] = cb[c0 + j];
        cwv[j] = *(const float4*)(cw + (c0 + j) * 4);
    }
    #pragma unroll
    for (int t = 0; t < 4; ++t) {
        const int lt = l - 3 + t;
        if (lt >= 0) {
            const short8 uv = *(const short8*)(u + (size_t)(s - 3 + t) * DI + c0);
            #pragma unroll
            for (int j = 0; j < 8; ++j) {
                const float wt = (t == 0) ? cwv[j].x : (t == 1) ? cwv[j].y
                               : (t == 2) ? cwv[j].z : cwv[j].w;
                acc[j] += bf2f((unsigned short)uv[j]) * wt;
            }
        }
    }
    float4 o0, o1; short8 ob;
    float res[8];
    #pragma unroll
    for (int j = 0; j < 8; ++j) {
        const float sig = 1.0f / (1.0f + __expf(-acc[j]));
        res[j] = acc[j] * sig;
        ob[j] = (short)f2bf(res[j]);
    }
    o0 = make_float4(res[0], res[1], res[2], res[3]);
    o1 = make_float4(res[4], res[5], res[6], res[7]);
    const size_t base = (size_t)s * DI + c0;
    *(float4*)(uc32 + base) = o0;
    *(float4*)(uc32 + base + 4) = o1;
    *(short8*)(uch + base) = ob;
}

// ---------------------------------------------------------------------------
// Chunked selective scan (3 passes).  See round-2 notes; changes:
// x_dbl stride 64, z is bf16, y written bf16 (feeds out_proj MFMA).
// ---------------------------------------------------------------------------
__global__ __launch_bounds__(256) void scan_p1(
    const float* __restrict__ delta, const float* __restrict__ uc,
    const float* __restrict__ xdbl, const float* __restrict__ A_log,
    float* __restrict__ P, float* __restrict__ Q)
{
    const int tid = threadIdx.x;
    const int cg = blockIdx.x & 7;
    const int k  = (blockIdx.x >> 3) & 15;
    const int b  = blockIdx.x >> 7;
    const int c  = (cg << 6) + (tid >> 2);
    const int nq = (tid & 3) << 2;

    const float4 al = *(const float4*)(A_log + c * DSTATE + nq);
    float4 a4;
    a4.x = -__expf(al.x); a4.y = -__expf(al.y);
    a4.z = -__expf(al.z); a4.w = -__expf(al.w);

    float4 h4 = {0, 0, 0, 0};
    float4 P4 = {1, 1, 1, 1};

    size_t off = ((size_t)(b * LSEQ + k * CHUNK)) * DI + c;
    size_t xo  = ((size_t)(b * LSEQ + k * CHUNK)) * XDLD;

    float  dA_ = delta[off],      uA_ = uc[off];
    float4 BA_ = *(const float4*)(xdbl + xo + DTRANK + nq);
    float  dB_ = delta[off + DI], uB_ = uc[off + DI];
    float4 BB_ = *(const float4*)(xdbl + xo + XDLD + DTRANK + nq);

    for (int l = 0; l < CHUNK; l += 2) {
        const size_t o2 = off + 2 * DI, x2 = xo + 2 * XDLD;
        float  dC_ = 0.f, uC_ = 0.f, dD_ = 0.f, uD_ = 0.f;
        float4 BC_ = {0,0,0,0}, BD_ = {0,0,0,0};
        if (l + 2 < CHUNK) {
            dC_ = delta[o2];      uC_ = uc[o2];
            BC_ = *(const float4*)(xdbl + x2 + DTRANK + nq);
            dD_ = delta[o2 + DI]; uD_ = uc[o2 + DI];
            BD_ = *(const float4*)(xdbl + x2 + XDLD + DTRANK + nq);
        }
        {
            float4 e;
            e.x = __expf(dA_ * a4.x); e.y = __expf(dA_ * a4.y);
            e.z = __expf(dA_ * a4.z); e.w = __expf(dA_ * a4.w);
            const float du = dA_ * uA_;
            h4.x = h4.x * e.x + du * BA_.x;
            h4.y = h4.y * e.y + du * BA_.y;
            h4.z = h4.z * e.z + du * BA_.z;
            h4.w = h4.w * e.w + du * BA_.w;
            P4.x *= e.x; P4.y *= e.y; P4.z *= e.z; P4.w *= e.w;
        }
        {
            float4 e;
            e.x = __expf(dB_ * a4.x); e.y = __expf(dB_ * a4.y);
            e.z = __expf(dB_ * a4.z); e.w = __expf(dB_ * a4.w);
            const float du = dB_ * uB_;
            h4.x = h4.x * e.x + du * BB_.x;
            h4.y = h4.y * e.y + du * BB_.y;
            h4.z = h4.z * e.z + du * BB_.z;
            h4.w = h4.w * e.w + du * BB_.w;
            P4.x *= e.x; P4.y *= e.y; P4.z *= e.z; P4.w *= e.w;
        }
        dA_ = dC_; uA_ = uC_; BA_ = BC_;
        dB_ = dD_; uB_ = uD_; BB_ = BD_;
        off = o2; xo = x2;
    }
    const size_t pi = (((size_t)(b * NCHUNK + k) * DI + c) << 4) + nq;
    *(float4*)(P + pi) = P4;
    *(float4*)(Q + pi) = h4;
}

__global__ __launch_bounds__(256) void scan_p2(
    const float* __restrict__ P, const float* __restrict__ Q,
    float* __restrict__ HS)
{
    const int t  = blockIdx.x * 256 + threadIdx.x;
    const int nq = (t & 3) << 2;
    const int c  = (t >> 2) & (DI - 1);
    const int b  = t >> 11;
    float4 hs = {0, 0, 0, 0};
    for (int k = 0; k < NCHUNK; ++k) {
        const size_t idx = (((size_t)(b * NCHUNK + k) * DI + c) << 4) + nq;
        if (k > 0) {
            const size_t ip = idx - ((size_t)DI << 4);
            const float4 p4 = *(const float4*)(P + ip);
            const float4 q4 = *(const float4*)(Q + ip);
            hs.x = hs.x * p4.x + q4.x;
            hs.y = hs.y * p4.y + q4.y;
            hs.z = hs.z * p4.z + q4.z;
            hs.w = hs.w * p4.w + q4.w;
        }
        *(float4*)(HS + idx) = hs;
    }
}

__global__ __launch_bounds__(256) void scan_p3(
    const float* __restrict__ delta, const float* __restrict__ uc,
    const float* __restrict__ xdbl, const unsigned short* __restrict__ z,
    const float* __restrict__ A_log, const float* __restrict__ Dskip,
    const float* __restrict__ HS, unsigned short* __restrict__ y)
{
    const int tid = threadIdx.x;
    const int cg = blockIdx.x & 7;
    const int k  = (blockIdx.x >> 3) & 15;
    const int b  = blockIdx.x >> 7;
    const int c  = (cg << 6) + (tid >> 2);
    const int nq = (tid & 3) << 2;

    const float4 al = *(const float4*)(A_log + c * DSTATE + nq);
    float4 a4;
    a4.x = -__expf(al.x); a4.y = -__expf(al.y);
    a4.z = -__expf(al.z); a4.w = -__expf(al.w);
    const float dsk = Dskip[c];

    const size_t pi = (((size_t)(b * NCHUNK + k) * DI + c) << 4) + nq;
    float4 h4 = *(const float4*)(HS + pi);

    size_t off = ((size_t)(b * LSEQ + k * CHUNK)) * DI + c;
    size_t xo  = ((size_t)(b * LSEQ + k * CHUNK)) * XDLD;

    float  dA_ = delta[off],      uA_ = uc[off];
    float  zA_ = bf2f(z[off]);
    float4 BA_ = *(const float4*)(xdbl + xo + DTRANK + nq);
    float4 CA_ = *(const float4*)(xdbl + xo + DTRANK + DSTATE + nq);
    float  dB_ = delta[off + DI], uB_ = uc[off + DI];
    float  zB_ = bf2f(z[off + DI]);
    float4 BB_ = *(const float4*)(xdbl + xo + XDLD + DTRANK + nq);
    float4 CB_ = *(const float4*)(xdbl + xo + XDLD + DTRANK + DSTATE + nq);

    for (int l = 0; l < CHUNK; l += 2) {
        const size_t o2 = off + 2 * DI, x2 = xo + 2 * XDLD;
        float  dC_ = 0.f, uC_ = 0.f, zC_ = 0.f, dD_ = 0.f, uD_ = 0.f, zD_ = 0.f;
        float4 BC_ = {0,0,0,0}, CC_ = {0,0,0,0}, BD_ = {0,0,0,0}, CD_ = {0,0,0,0};
        if (l + 2 < CHUNK) {
            dC_ = delta[o2];      uC_ = uc[o2];      zC_ = bf2f(z[o2]);
            BC_ = *(const float4*)(xdbl + x2 + DTRANK + nq);
            CC_ = *(const float4*)(xdbl + x2 + DTRANK + DSTATE + nq);
            dD_ = delta[o2 + DI]; uD_ = uc[o2 + DI]; zD_ = bf2f(z[o2 + DI]);
            BD_ = *(const float4*)(xdbl + x2 + XDLD + DTRANK + nq);
            CD_ = *(const float4*)(xdbl + x2 + XDLD + DTRANK + DSTATE + nq);
        }
        {
            float4 e;
            e.x = __expf(dA_ * a4.x); e.y = __expf(dA_ * a4.y);
            e.z = __expf(dA_ * a4.z); e.w = __expf(dA_ * a4.w);
            const float du = dA_ * uA_;
            h4.x = h4.x * e.x + du * BA_.x;
            h4.y = h4.y * e.y + du * BA_.y;
            h4.z = h4.z * e.z + du * BA_.z;
            h4.w = h4.w * e.w + du * BA_.w;
            float yp = h4.x * CA_.x + h4.y * CA_.y + h4.z * CA_.z + h4.w * CA_.w;
            yp += __shfl_xor(yp, 1);
            yp += __shfl_xor(yp, 2);
            if ((tid & 3) == 0) {
                const float sg = 1.0f / (1.0f + __expf(-zA_));
                y[off] = f2bf((yp + uA_ * dsk) * (zA_ * sg));
            }
        }
        {
            float4 e;
            e.x = __expf(dB_ * a4.x); e.y = __expf(dB_ * a4.y);
            e.z = __expf(dB_ * a4.z); e.w = __expf(dB_ * a4.w);
            const float du = dB_ * uB_;
            h4.x = h4.x * e.x + du * BB_.x;
            h4.y = h4.y * e.y + du * BB_.y;
            h4.z = h4.z * e.z + du * BB_.z;
            h4.w = h4.w * e.w + du * BB_.w;
            float yp = h4.x * CB_.x + h4.y * CB_.y + h4.z * CB_.z + h4.w * CB_.w;
            yp += __shfl_xor(yp, 1);
            yp += __shfl_xor(yp, 2);
            if ((tid & 3) == 0) {
                const float sg = 1.0f / (1.0f + __expf(-zB_));
                y[off + DI] = f2bf((yp + uB_ * dsk) * (zB_ * sg));
            }
        }
        dA_ = dC_; uA_ = uC_; zA_ = zC_; BA_ = BC_; CA_ = CC_;
        dB_ = dD_; uB_ = uD_; zB_ = zD_; BB_ = BD_; CB_ = CD_;
        off = o2; xo = x2;
    }
}

// ---------------------------------------------------------------------------
// LayerNorm over rows of 256; optional bf16 side-output.
// ---------------------------------------------------------------------------
__global__ __launch_bounds__(256) void layernorm256_kernel(
    const float* __restrict__ in, const float* __restrict__ g,
    const float* __restrict__ b, float* __restrict__ out,
    unsigned short* __restrict__ out16)
{
    const int wave = threadIdx.x >> 6;
    const int lane = threadIdx.x & 63;
    const int row  = blockIdx.x * 4 + wave;

    const float4 v = ((const float4*)(in + (size_t)row * DM))[lane];
    float s  = v.x + v.y + v.z + v.w;
    float sq = v.x * v.x + v.y * v.y + v.z * v.z + v.w * v.w;
    #pragma unroll
    for (int o = 1; o < 64; o <<= 1) {
        s  += __shfl_xor(s, o);
        sq += __shfl_xor(sq, o);
    }
    const float mu  = s * (1.0f / 256.0f);
    const float var = sq * (1.0f / 256.0f) - mu * mu;
    const float rs  = rsqrtf(var + 1e-12f);

    const float4 gg = ((const float4*)g)[lane];
    const float4 bb = ((const float4*)b)[lane];
    float4 o4;
    o4.x = (v.x - mu) * rs * gg.x + bb.x;
    o4.y = (v.y - mu) * rs * gg.y + bb.y;
    o4.z = (v.z - mu) * rs * gg.z + bb.z;
    o4.w = (v.w - mu) * rs * gg.w + bb.w;
    ((float4*)(out + (size_t)row * DM))[lane] = o4;
    if (out16) {
        uint2 p;
        p.x = (unsigned int)f2bf(o4.x) | ((unsigned int)f2bf(o4.y) << 16);
        p.y = (unsigned int)f2bf(o4.z) | ((unsigned int)f2bf(o4.w) << 16);
        *(uint2*)(out16 + (size_t)row * DM + lane * 4) = p;
    }
}

// ---------------------------------------------------------------------------
extern "C" void kernel_launch(void* const* d_in, const int* in_sizes, int n_in,
                              void* d_out, int out_size, void* d_ws, size_t ws_size,
                              hipStream_t stream)
{
    const float* x          = (const float*)d_in[0];
    const float* in_proj_w  = (const float*)d_in[1];
    const float* conv_w     = (const float*)d_in[2];
    const float* conv_b     = (const float*)d_in[3];
    const float* x_proj_w   = (const float*)d_in[4];
    const float* dt_proj_w  = (const float*)d_in[5];
    const float* dt_proj_b  = (const float*)d_in[6];
    const float* A_log      = (const float*)d_in[7];
    const float* Dskip      = (const float*)d_in[8];
    const float* out_proj_w = (const float*)d_in[9];
    const float* ln1_g      = (const float*)d_in[10];
    const float* ln1_b      = (const float*)d_in[11];
    const float* w1         = (const float*)d_in[12];
    const float* b1         = (const float*)d_in[13];
    const float* w2         = (const float*)d_in[14];
    const float* b2         = (const float*)d_in[15];
    const float* ln2_g      = (const float*)d_in[16];
    const float* ln2_b      = (const float*)d_in[17];
    float* out = (float*)d_out;
    char*  ws8 = (char*)d_ws;

    // Workspace slabs (bytes), total ~245 MB:
    //  slab0 [  0M,  32M): u bf16            -> later F2 f32 (pre-LN2)
    //  slab1 [ 32M,  64M): z bf16            -> later M f32 (pre-LN1)
    //  slab2 [ 64M, 128M): uc f32            -> later h1 f32 + h1 bf16
    //  slab3 [128M, 160M): uc bf16           -> y bf16 (in-place)
    //  slab4 [160M, 224M): delta f32         -> later FF bf16
    //  slab5 [224M, 232M): x_dbl f32 [S,64]
    //  slab6 [232M, ...):  bf16 weights
    unsigned short* bufU   = (unsigned short*)(ws8);
    unsigned short* bufZ   = (unsigned short*)(ws8 + 33554432);
    float*          bufUC  = (float*)(ws8 + 67108864);
    unsigned short* bufUCh = (unsigned short*)(ws8 + 134217728);
    float*          bufDel = (float*)(ws8 + 167772160);
    float*          bufXD  = (float*)(ws8 + 234881024);
    unsigned short* wb     = (unsigned short*)(ws8 + 243269632);

    float*          bufM   = (float*)(ws8 + 33554432);           // over z
    float*          bufH1  = (float*)(ws8 + 67108864);           // over uc
    unsigned short* bufH1h = (unsigned short*)(ws8 + 100663296); // over uc (hi half)
    unsigned short* bufFF  = (unsigned short*)(ws8 + 167772160); // over delta
    float*          bufF2  = (float*)(ws8);                      // over u
    unsigned short* bufY   = bufUCh;                             // y over uc bf16

    unsigned short* wInP16 = wb;
    unsigned short* wXP16  = wb + 262144;
    unsigned short* wOP16  = wb + 286720;
    unsigned short* wW116  = wb + 417792;
    unsigned short* wW216  = wb + 679936;

    // d_out scratch: x bf16 [S,256] (dead after in_proj), then P/Q/HS f32.
    unsigned short* x16 = (unsigned short*)d_out;
    float* bufP  = out;
    float* bufQ  = out + (size_t)NBATCH * NCHUNK * DI * DSTATE;
    float* bufHS = out + (size_t)2 * NBATCH * NCHUNK * DI * DSTATE;

    const dim3 blk(256);
    const int MT = S_TOTAL / 128;   // 256 row tiles for MFMA GEMMs

    // 0) cast x + weights to bf16
    convert_kernel<<<dim3(36448), blk, 0, stream>>>(
        x, in_proj_w, x_proj_w, out_proj_w, w1, w2, x16, wb);

    // 1) in_proj -> u (bf16), z (bf16)
    gemm_bf16<EPI_NONE, true><<<dim3(4, MT), blk, 0, stream>>>(
        x16, DM, wInP16, DM, nullptr, nullptr, 0, bufU, DI, 512, DM, 511);
    gemm_bf16<EPI_NONE, true><<<dim3(4, MT), blk, 0, stream>>>(
        x16, DM, wInP16 + (size_t)DI * DM, DM, nullptr, nullptr, 0, bufZ, DI, 512, DM, 511);

    // 2) depthwise causal conv + SiLU -> uc f32 + uc bf16
    conv_silu_kernel<<<dim3(S_TOTAL * 64 / 256), blk, 0, stream>>>(
        bufU, conv_w, conv_b, bufUC, bufUCh);

    // 3) x_proj -> x_dbl f32 [S,64] (48 valid cols)
    gemm_bf16<EPI_NONE, false><<<dim3(1, MT), blk, 0, stream>>>(
        bufUCh, DI, wXP16, DI, nullptr, nullptr, 0, bufXD, XDLD, 64, DI, 47);

    // 4) dt_proj + softplus -> delta f32 (K=16, f32 vector GEMM)
    gemm_f32<EPI_SOFTPLUS_BIAS><<<dim3(8, S_TOTAL / 64), blk, 0, stream>>>(
        bufXD, XDLD, dt_proj_w, dt_proj_b, bufDel, DI, S_TOTAL, DI, DTRANK);

    // 5) chunked selective scan -> y bf16
    scan_p1<<<dim3(NBATCH * NCHUNK * (DI / 64)), blk, 0, stream>>>(
        bufDel, bufUC, bufXD, A_log, bufP, bufQ);
    scan_p2<<<dim3(NBATCH * DI * 4 / 256), blk, 0, stream>>>(
        bufP, bufQ, bufHS);
    scan_p3<<<dim3(NBATCH * NCHUNK * (DI / 64)), blk, 0, stream>>>(
        bufDel, bufUC, bufXD, bufZ, A_log, Dskip, bufHS, bufY);

    // 6) out_proj + residual x -> M f32 (pre-LN1)
    gemm_bf16<EPI_RESID, false><<<dim3(2, MT), blk, 0, stream>>>(
        bufY, DI, wOP16, DI, nullptr, x, DM, bufM, DM, 256, DI, 255);

    // 7) LN1 -> h1 f32 + h1 bf16
    layernorm256_kernel<<<dim3(S_TOTAL / 4), blk, 0, stream>>>(
        bufM, ln1_g, ln1_b, bufH1, bufH1h);

    // 8) ff1: gelu(h1 @ w1^T + b1) -> FF bf16
    gemm_bf16<EPI_GELU_BIAS, true><<<dim3(8, MT), blk, 0, stream>>>(
        bufH1h, DM, wW116, DM, b1, nullptr, 0, bufFF, 1024, 1024, DM, 1023);

    // 9) ff2 + b2 + h1 -> F2 f32 (pre-LN2)
    gemm_bf16<EPI_BIAS_RESID, false><<<dim3(2, MT), blk, 0, stream>>>(
        bufFF, 1024, wW216, 1024, b2, bufH1, DM, bufF2, DM, 256, 1024, 255);

    // 10) LN2 -> out
    layernorm256_kernel<<<dim3(S_TOTAL / 4), blk, 0, stream>>>(
        bufF2, ln2_g, ln2_b, out, nullptr);
}